// Round 1
// 351.590 us; speedup vs baseline: 1.0578x; 1.0578x over previous
//
#include <hip/hip_runtime.h>
#include <hip/hip_bf16.h>

#define Bb 4
#define Nn 4096
#define C1 320
#define C2 256
#define Hh 5
#define HD 64
#define Mm (Bb*Nn)   // 16384

using bf16 = __hip_bfloat16;
typedef __attribute__((ext_vector_type(8))) short  short8;   // 8 bf16 = one MFMA A/B frag
typedef __attribute__((ext_vector_type(4))) short  short4_;
typedef __attribute__((ext_vector_type(4))) float  f32x4;    // 16x16 MFMA C/D frag
typedef __attribute__((ext_vector_type(16))) float f32x16;   // 32x32 MFMA C/D frag

__device__ __forceinline__ short f2s(float f) {
    bf16 h = __float2bfloat16(f);
    short s;
    __builtin_memcpy(&s, &h, 2);
    return s;
}

__device__ __forceinline__ float fexp2(float x) {
#if __has_builtin(__builtin_amdgcn_exp2f)
    return __builtin_amdgcn_exp2f(x);
#else
    return exp2f(x);
#endif
}

// XOR-swizzled LDS tile addressing: 64-elem rows, 8 blocks of 8 bf16 (16B).
// physical elem offset of (row, logical block bb) = row*64 + (bb ^ (row&7))*8
__device__ __forceinline__ int swz(int row, int bb) {
    return row * 64 + ((bb ^ (row & 7)) << 3);
}

// pack two f32 -> one dword of 2 bf16 (src0 -> low half)
__device__ __forceinline__ unsigned cvtpk(float lo, float hi) {
    unsigned r;
    asm("v_cvt_pk_bf16_f32 %0, %1, %2" : "=v"(r) : "v"(lo), "v"(hi));
    return r;
}

// swap: a[lanes 32..63] <- b[lanes 0..31]; b[lanes 0..31] <- a[lanes 32..63]
__device__ __forceinline__ void plswap(unsigned &a, unsigned &b) {
#if __has_builtin(__builtin_amdgcn_permlane32_swap)
    auto r = __builtin_amdgcn_permlane32_swap(a, b, false, false);
    a = r[0]; b = r[1];
#else
    asm("v_permlane32_swap_b32 %0, %1" : "+v"(a), "+v"(b));
#endif
}

__device__ __forceinline__ short8 mk8(unsigned d0, unsigned d1, unsigned d2, unsigned d3) {
    union { unsigned u[4]; short8 s; } u;
    u.u[0] = d0; u.u[1] = d1; u.u[2] = d2; u.u[3] = d3;
    return u.s;
}

// ---------------- fp32 -> bf16 convert, all 8 tensors in one launch ----------------
struct CvtArgs {
    const float* s[8];
    bf16* d[8];
    int off[9];   // cumulative offsets, off[8] = total
};

__global__ void cvt_all(CvtArgs a) {
    int i = (blockIdx.x * blockDim.x + threadIdx.x) * 4;
    if (i >= a.off[8]) return;
    int seg = 0;
    #pragma unroll
    for (int k = 1; k < 8; ++k) seg += (i >= a.off[k]);
    int j = i - a.off[seg];
    float4 v = *(const float4*)(a.s[seg] + j);
    short4_ o = { f2s(v.x), f2s(v.y), f2s(v.z), f2s(v.w) };
    *(short4_*)(a.d[seg] + j) = o;
}

// ---------------- generic GEMM: C[M,n0..] = A[M,K] x W[Nout,K]^T ----------------
// mode 0: store bf16*oscale to O1[row*320+col]
// mode 1: col<320 -> O1 (K part, [M,320]); col>=320 -> O2 = V transposed [B,H,64,N]
// mode 2: fp32 out Of[row*640 + ooff + col] + bias[col]
__global__ __launch_bounds__(256) void gemm_bt(
    const bf16* __restrict__ A, const bf16* __restrict__ W,
    int K, int mode, float oscale,
    bf16* __restrict__ O1, bf16* __restrict__ O2,
    const float* __restrict__ bias, float* __restrict__ Of, int ooff)
{
    __shared__ bf16 la[64 * 64];
    __shared__ bf16 lw[64 * 64];
    const int m0 = blockIdx.x * 64, n0 = blockIdx.y * 64;
    const int t = threadIdx.x;
    const int wave = t >> 6, lane = t & 63, l16 = lane & 15, quad = lane >> 4;
    const int sr = t >> 3, sb = t & 7;

    f32x4 acc[4] = {{0.f,0.f,0.f,0.f},{0.f,0.f,0.f,0.f},{0.f,0.f,0.f,0.f},{0.f,0.f,0.f,0.f}};

    const int nk = K >> 6;
    // register prefetch of first k-tile
    short8 ra0 = *(const short8*)(A + (size_t)(m0 + sr) * K + sb * 8);
    short8 ra1 = *(const short8*)(A + (size_t)(m0 + sr + 32) * K + sb * 8);
    short8 rw0 = *(const short8*)(W + (size_t)(n0 + sr) * K + sb * 8);
    short8 rw1 = *(const short8*)(W + (size_t)(n0 + sr + 32) * K + sb * 8);

    for (int kt = 0; kt < nk; ++kt) {
        __syncthreads();
        *(short8*)&la[swz(sr, sb)]      = ra0;
        *(short8*)&la[swz(sr + 32, sb)] = ra1;
        *(short8*)&lw[swz(sr, sb)]      = rw0;
        *(short8*)&lw[swz(sr + 32, sb)] = rw1;
        __syncthreads();
        if (kt + 1 < nk) {
            const int k0 = (kt + 1) * 64;
            ra0 = *(const short8*)(A + (size_t)(m0 + sr) * K + k0 + sb * 8);
            ra1 = *(const short8*)(A + (size_t)(m0 + sr + 32) * K + k0 + sb * 8);
            rw0 = *(const short8*)(W + (size_t)(n0 + sr) * K + k0 + sb * 8);
            rw1 = *(const short8*)(W + (size_t)(n0 + sr + 32) * K + k0 + sb * 8);
        }
        const int arow = wave * 16 + l16;
        short8 a0 = *(const short8*)&la[swz(arow, quad)];
        short8 a1 = *(const short8*)&la[swz(arow, quad + 4)];
        #pragma unroll
        for (int nt = 0; nt < 4; ++nt) {
            const int brow = nt * 16 + l16;
            short8 b0 = *(const short8*)&lw[swz(brow, quad)];
            short8 b1 = *(const short8*)&lw[swz(brow, quad + 4)];
            acc[nt] = __builtin_amdgcn_mfma_f32_16x16x32_bf16(a0, b0, acc[nt], 0, 0, 0);
            acc[nt] = __builtin_amdgcn_mfma_f32_16x16x32_bf16(a1, b1, acc[nt], 0, 0, 0);
        }
    }

    const int mrow = m0 + wave * 16 + quad * 4;
    if (mode == 2) {
        #pragma unroll
        for (int nt = 0; nt < 4; ++nt) {
            int col = n0 + nt * 16 + l16;
            float bv = bias[col];
            #pragma unroll
            for (int r = 0; r < 4; ++r)
                Of[(size_t)(mrow + r) * 640 + ooff + col] = acc[nt][r] + bv;
        }
    } else if (mode == 0 || n0 < C1) {
        #pragma unroll
        for (int nt = 0; nt < 4; ++nt) {
            int col = n0 + nt * 16 + l16;
            #pragma unroll
            for (int r = 0; r < 4; ++r)
                O1[(size_t)(mrow + r) * C1 + col] = __float2bfloat16(acc[nt][r] * oscale);
        }
    } else {
        // V part: write transposed [B,H,64,N]
        #pragma unroll
        for (int nt = 0; nt < 4; ++nt) {
            int col = n0 + nt * 16 + l16 - C1;
            int h = col >> 6, d = col & 63;
            #pragma unroll
            for (int r = 0; r < 4; ++r) {
                int m = mrow + r;
                int b = m >> 12, n = m & (Nn - 1);
                O2[((size_t)(b * Hh + h) * 64 + d) * Nn + n] = __float2bfloat16(acc[nt][r]);
            }
        }
    }
}

// ---------------- flash attention, both branches in one launch ----------------
// m214-style 32x32 structure: block = 256 q-rows, 4 waves x 64 q (2 q-blocks of 32).
// S computed TRANSPOSED via mfma_32x32x16(K, Q): lane holds a full P-row slice
// (q = lane&31, k = (r&3)+8*(r>>2)+4*hi). P converted to bf16 A-frags entirely
// in-register: v_cvt_pk_bf16_f32 pairs + v_permlane32_swap_b32 (no P LDS tile).
// K/V staged in 16KB swizzled LDS (reg-prefetched one tile ahead); each K/V
// fragment read once per wave and reused by both q-blocks -> LDS reads/FLOP
// halved vs the 16x16 version. Fixed m=0 softmax (Q pre-scaled by 0.125*log2e).
__global__ __launch_bounds__(256, 2) void flash_kernel(
    const bf16* __restrict__ Q1, const bf16* __restrict__ K1,
    const bf16* __restrict__ V1, bf16* __restrict__ Y1,
    const bf16* __restrict__ Q2, const bf16* __restrict__ K2,
    const bf16* __restrict__ V2, bf16* __restrict__ Y2)
{
    __shared__ bf16 lk[64 * 64];        // K tile [k][d], swizzled
    __shared__ bf16 lv[64 * 64];        // V tile [d][k], swizzled (from pre-transposed Vt)
    const int qt = blockIdx.x, h = blockIdx.y, z = blockIdx.z;
    const int b = z & 3, branch = z >> 2;
    const bf16* Q  = branch ? Q2 : Q1;
    const bf16* Km = branch ? K2 : K1;
    const bf16* Vt = branch ? V2 : V1;
    bf16*       Yo = branch ? Y2 : Y1;

    const int t = threadIdx.x;
    const int wave = t >> 6, lane = t & 63;
    const int l32 = lane & 31, hi = lane >> 5;
    const int sr = t >> 3, sb = t & 7;

    const int qrow0 = qt * 256 + wave * 64;    // this wave's 64 q rows

    // Q B-frags for the whole loop: [qb][ksd] -> Q[qrow0+qb*32+l32][ksd*16+hi*8 ..+7]
    short8 qf[2][4];
    #pragma unroll
    for (int qb = 0; qb < 2; ++qb) {
        const bf16* qptr = Q + (size_t)(b * Nn + qrow0 + qb * 32 + l32) * C1 + h * HD + hi * 8;
        #pragma unroll
        for (int ksd = 0; ksd < 4; ++ksd)
            qf[qb][ksd] = *(const short8*)(qptr + ksd * 16);
    }

    f32x16 o[2][2];                    // [qb][db] PV accumulators
    #pragma unroll
    for (int qb = 0; qb < 2; ++qb)
        #pragma unroll
        for (int db = 0; db < 2; ++db)
            o[qb][db] = (f32x16){0.f,0.f,0.f,0.f,0.f,0.f,0.f,0.f,0.f,0.f,0.f,0.f,0.f,0.f,0.f,0.f};
    float lsum[2] = {0.f, 0.f};

    const bf16* Kbase = Km + (size_t)b * Nn * C1 + h * HD;
    const bf16* Vbase = Vt + (size_t)(b * Hh + h) * 64 * Nn;

    // register prefetch of the first k-tile staging data
    short8 rk0 = *(const short8*)(Kbase + (size_t)sr * C1 + sb * 8);
    short8 rk1 = *(const short8*)(Kbase + (size_t)(sr + 32) * C1 + sb * 8);
    short8 rv0 = *(const short8*)(Vbase + (size_t)sr * Nn + sb * 8);
    short8 rv1 = *(const short8*)(Vbase + (size_t)(sr + 32) * Nn + sb * 8);

    const int NT = Nn / 64;
    for (int kt = 0; kt < NT; ++kt) {
        __syncthreads();                         // prior iter's readers done
        *(short8*)&lk[swz(sr, sb)]      = rk0;
        *(short8*)&lk[swz(sr + 32, sb)] = rk1;
        *(short8*)&lv[swz(sr, sb)]      = rv0;
        *(short8*)&lv[swz(sr + 32, sb)] = rv1;
        __syncthreads();
        if (kt + 1 < NT) {                       // prefetch next tile; overlaps compute
            const int kn = (kt + 1) * 64;
            rk0 = *(const short8*)(Kbase + (size_t)(kn + sr) * C1 + sb * 8);
            rk1 = *(const short8*)(Kbase + (size_t)(kn + sr + 32) * C1 + sb * 8);
            rv0 = *(const short8*)(Vbase + (size_t)sr * Nn + kn + sb * 8);
            rv1 = *(const short8*)(Vbase + (size_t)(sr + 32) * Nn + kn + sb * 8);
        }

        #pragma unroll
        for (int kb = 0; kb < 2; ++kb) {
            // K a-frags (row k = kb*32 + l32, d = ksd*16 + hi*8), reused by both qb
            short8 ka[4];
            #pragma unroll
            for (int ksd = 0; ksd < 4; ++ksd)
                ka[ksd] = *(const short8*)&lk[swz(kb * 32 + l32, ksd * 2 + hi)];

            short8 pa[2][2];   // [qb][ks] PV A-frags, built fully in-register
            #pragma unroll
            for (int qb = 0; qb < 2; ++qb) {
                f32x16 s = (f32x16){0.f,0.f,0.f,0.f,0.f,0.f,0.f,0.f,0.f,0.f,0.f,0.f,0.f,0.f,0.f,0.f};
                #pragma unroll
                for (int ksd = 0; ksd < 4; ++ksd)
                    s = __builtin_amdgcn_mfma_f32_32x32x16_bf16(ka[ksd], qf[qb][ksd], s, 0, 0, 0);
                // p[r] = P[q = l32][k = (r&3) + 8*(r>>2) + 4*hi] (within this kb)
                float p[16];
                #pragma unroll
                for (int r = 0; r < 16; ++r) p[r] = fexp2(s[r]);
                lsum[qb] += (((p[0]+p[1])+(p[2]+p[3])) + ((p[4]+p[5])+(p[6]+p[7])))
                          + (((p[8]+p[9])+(p[10]+p[11])) + ((p[12]+p[13])+(p[14]+p[15])));
                // ks=0 (k 0..15): dw0/dw2 from one swap, dw1/dw3 from the other
                unsigned d0 = cvtpk(p[0],  p[1]),  d2 = cvtpk(p[4],  p[5]);
                plswap(d0, d2);
                unsigned d1 = cvtpk(p[2],  p[3]),  d3 = cvtpk(p[6],  p[7]);
                plswap(d1, d3);
                pa[qb][0] = mk8(d0, d1, d2, d3);
                // ks=1 (k 16..31)
                unsigned e0 = cvtpk(p[8],  p[9]),  e2 = cvtpk(p[12], p[13]);
                plswap(e0, e2);
                unsigned e1 = cvtpk(p[10], p[11]), e3 = cvtpk(p[14], p[15]);
                plswap(e1, e3);
                pa[qb][1] = mk8(e0, e1, e2, e3);
            }

            // O += P V ; each V b-frag read once, reused by both qb
            #pragma unroll
            for (int ks = 0; ks < 2; ++ks) {
                #pragma unroll
                for (int db = 0; db < 2; ++db) {
                    short8 bv = *(const short8*)&lv[swz(db * 32 + l32, kb * 4 + ks * 2 + hi)];
                    o[0][db] = __builtin_amdgcn_mfma_f32_32x32x16_bf16(pa[0][ks], bv, o[0][db], 0, 0, 0);
                    o[1][db] = __builtin_amdgcn_mfma_f32_32x32x16_bf16(pa[1][ks], bv, o[1][db], 0, 0, 0);
                }
            }
        }
    }

    // epilogue: complete row sums across hi halves, redistribute to C/D rows, store
    #pragma unroll
    for (int qb = 0; qb < 2; ++qb) {
        float l = lsum[qb] + __shfl_xor(lsum[qb], 32, 64);  // row sum for q = qb*32 + l32
        float inv = 1.0f / l;
        #pragma unroll
        for (int r = 0; r < 16; ++r) {
            const int qr = (r & 3) + 8 * (r >> 2) + 4 * hi;  // C/D row for this reg
            float invr = __shfl(inv, qr, 64);
            size_t row = (size_t)(b * Nn + qrow0 + qb * 32 + qr);
            #pragma unroll
            for (int db = 0; db < 2; ++db)
                Yo[row * C1 + h * HD + db * 32 + l32] = __float2bfloat16(o[qb][db][r] * invr);
        }
    }
}

extern "C" void kernel_launch(void* const* d_in, const int* in_sizes, int n_in,
                              void* d_out, int out_size, void* d_ws, size_t ws_size,
                              hipStream_t stream)
{
    const float* x1   = (const float*)d_in[0];
    const float* x2   = (const float*)d_in[1];
    const float* q1w  = (const float*)d_in[2];
    const float* q2w  = (const float*)d_in[3];
    const float* kv1w = (const float*)d_in[4];
    const float* kv2w = (const float*)d_in[5];
    const float* p1w  = (const float*)d_in[6];
    const float* p1b  = (const float*)d_in[7];
    const float* p2w  = (const float*)d_in[8];
    const float* p2b  = (const float*)d_in[9];
    float* out = (float*)d_out;

    bf16* ws = (bf16*)d_ws;
    size_t o = 0;
    bf16* x1b  = ws + o; o += (size_t)Mm * C1;
    bf16* x2b  = ws + o; o += (size_t)Mm * C2;
    bf16* wq1  = ws + o; o += C1 * C1;
    bf16* wq2  = ws + o; o += C1 * C2;
    bf16* wkv1 = ws + o; o += 2 * C1 * C2;
    bf16* wkv2 = ws + o; o += 2 * C1 * C1;
    bf16* wp1  = ws + o; o += C1 * C1;
    bf16* wp2  = ws + o; o += C1 * C1;
    bf16* Q1   = ws + o; o += (size_t)Mm * C1;
    bf16* K1   = ws + o; o += (size_t)Mm * C1;
    bf16* V1t  = ws + o; o += (size_t)Mm * C1;      // [B,H,64,N]
    bf16* Q2   = ws + o; o += (size_t)Mm * C1;
    bf16* K2   = ws + o; o += (size_t)Mm * C1;
    bf16* V2t  = ws + o; o += (size_t)Mm * C1;
    bf16* Y1   = ws + o; o += (size_t)Mm * C1;
    bf16* Y2   = ws + o; o += (size_t)Mm * C1;
    (void)ws_size; (void)in_sizes; (void)n_in; (void)out_size;

    // one convert launch for all 8 fp32->bf16 tensors
    CvtArgs ca;
    ca.s[0] = x1;   ca.d[0] = x1b;  int n0 = Mm * C1;
    ca.s[1] = x2;   ca.d[1] = x2b;  int n1 = Mm * C2;
    ca.s[2] = q1w;  ca.d[2] = wq1;  int n2 = C1 * C1;
    ca.s[3] = q2w;  ca.d[3] = wq2;  int n3 = C1 * C2;
    ca.s[4] = kv1w; ca.d[4] = wkv1; int n4 = 2 * C1 * C2;
    ca.s[5] = kv2w; ca.d[5] = wkv2; int n5 = 2 * C1 * C1;
    ca.s[6] = p1w;  ca.d[6] = wp1;  int n6 = C1 * C1;
    ca.s[7] = p2w;  ca.d[7] = wp2;  int n7 = C1 * C1;
    int ns[8] = {n0, n1, n2, n3, n4, n5, n6, n7};
    ca.off[0] = 0;
    for (int i = 0; i < 8; ++i) ca.off[i + 1] = ca.off[i] + ns[i];
    int total = ca.off[8];
    cvt_all<<<dim3((total / 4 + 255) / 256), 256, 0, stream>>>(ca);

    const float QS = 0.125f * 1.4426950408889634f;   // scale * log2(e), folded into Q

    // Q/KV projections
    gemm_bt<<<dim3(Mm / 64, C1 / 64), 256, 0, stream>>>(x1b, wq1, C1, 0, QS, Q1, nullptr, nullptr, nullptr, 0);
    gemm_bt<<<dim3(Mm / 64, (2 * C1) / 64), 256, 0, stream>>>(x2b, wkv1, C2, 1, 1.0f, K1, V1t, nullptr, nullptr, 0);
    gemm_bt<<<dim3(Mm / 64, C1 / 64), 256, 0, stream>>>(x2b, wq2, C2, 0, QS, Q2, nullptr, nullptr, nullptr, 0);
    gemm_bt<<<dim3(Mm / 64, (2 * C1) / 64), 256, 0, stream>>>(x1b, wkv2, C1, 1, 1.0f, K2, V2t, nullptr, nullptr, 0);

    // attention, both branches in one launch; 256 q-rows per block (4 waves x 64 q)
    flash_kernel<<<dim3(Nn / 256, Hh, 2 * Bb), 256, 0, stream>>>(Q1, K1, V1t, Y1, Q2, K2, V2t, Y2);

    // output projections (fused bias + concat layout)
    gemm_bt<<<dim3(Mm / 64, C1 / 64), 256, 0, stream>>>(Y1, wp1, C1, 2, 1.0f, nullptr, nullptr, p1b, out, 0);
    gemm_bt<<<dim3(Mm / 64, C1 / 64), 256, 0, stream>>>(Y2, wp2, C1, 2, 1.0f, nullptr, nullptr, p2b, out, C1);
}